// Round 4
// baseline (1057.063 us; speedup 1.0000x reference)
//
#include <hip/hip_runtime.h>
#include <stdint.h>
#include <math.h>

// Problem dims
static constexpr int BDIM = 2048;   // batch B
static constexpr int HDIM = 2048;   // hidden H
static constexpr int DDIM = 512;    // input dim D
static constexpr int NSAMP = 32;    // N_SAMPLE

// d_out layout (float elements, concatenated in return order)
static constexpr size_t OFF_H  = 0;
static constexpr size_t OFF_Z  = (size_t)BDIM * HDIM;                  // 4194304
static constexpr size_t OFF_OH = OFF_Z + (size_t)BDIM * HDIM;          // 8388608
static constexpr size_t OFF_XD = OFF_OH + (size_t)NSAMP * BDIM * HDIM; // 142606336
static constexpr size_t OFF_W  = OFF_XD + (size_t)NSAMP * BDIM * DDIM; // 176160768

// d_ws layout (floats): Wt [2048*512], samp int[65536], temp [65536], rowDelta [2048]
static constexpr size_t WS_WT    = 0;
static constexpr size_t WS_SAMP  = (size_t)HDIM * DDIM;       // 1048576
static constexpr size_t WS_TEMP  = WS_SAMP + 65536;
static constexpr size_t WS_DELTA = WS_TEMP + 65536;

// ---------------- GEMM: h = x @ W  (fp32, M=2048 K=512 N=2048) ----------------
__global__ __launch_bounds__(256) void gemm_kernel(const float* __restrict__ x,
                                                   const float* __restrict__ W,
                                                   float* __restrict__ h) {
  __shared__ float As[16][68];  // [k][m], pad 68 keeps 16B align + spreads banks
  __shared__ float Bs[16][68];  // [k][n]
  const int tid = threadIdx.x;
  const int bm = blockIdx.y, bn = blockIdx.x;
  const int tm = tid >> 4, tn = tid & 15;  // 16x16 threads, 4x4 micro-tile
  float acc[4][4] = {};

  const int a_m = tid >> 2;            // 0..63
  const int a_k = (tid & 3) << 2;      // 0,4,8,12
  const int b_k = tid >> 4;            // 0..15
  const int b_n = (tid & 15) << 2;     // 0..60

  const float* xp = x + (size_t)(bm * 64 + a_m) * DDIM + a_k;
  const float* wp = W + (size_t)b_k * HDIM + bn * 64 + b_n;

  for (int k0 = 0; k0 < DDIM; k0 += 16) {
    float4 av = *(const float4*)(xp + k0);
    float4 bv = *(const float4*)(wp + (size_t)k0 * HDIM);
    As[a_k + 0][a_m] = av.x;
    As[a_k + 1][a_m] = av.y;
    As[a_k + 2][a_m] = av.z;
    As[a_k + 3][a_m] = av.w;
    *(float4*)&Bs[b_k][b_n] = bv;
    __syncthreads();
#pragma unroll
    for (int k = 0; k < 16; ++k) {
      float4 a = *(const float4*)&As[k][tm << 2];
      float4 b = *(const float4*)&Bs[k][tn << 2];
      float aa[4] = {a.x, a.y, a.z, a.w};
      float bb[4] = {b.x, b.y, b.z, b.w};
#pragma unroll
      for (int i = 0; i < 4; ++i)
#pragma unroll
        for (int j = 0; j < 4; ++j) acc[i][j] = fmaf(aa[i], bb[j], acc[i][j]);
    }
    __syncthreads();
  }
#pragma unroll
  for (int i = 0; i < 4; ++i) {
    float4 v = {acc[i][0], acc[i][1], acc[i][2], acc[i][3]};
    *(float4*)&h[(size_t)(bm * 64 + (tm << 2) + i) * HDIM + bn * 64 + (tn << 2)] = v;
  }
}

// ---------------- Softmax rows + per-row z-spread ----------------
__global__ __launch_bounds__(256) void softmax_kernel(const float* __restrict__ h,
                                                      float* __restrict__ z,
                                                      float* __restrict__ rowDelta) {
  const int b = blockIdx.x;
  const int tid = threadIdx.x;
  const float* row = h + (size_t)b * HDIM;
  float* zrow = z + (size_t)b * HDIM;
  __shared__ float red[256], red2[256];

  float vals[8];
  float vmax = -INFINITY, vmin = INFINITY;
#pragma unroll
  for (int k = 0; k < 8; ++k) {
    float v = row[tid + (k << 8)];
    vals[k] = v;
    vmax = fmaxf(vmax, v);
    vmin = fminf(vmin, v);
  }
  red[tid] = vmax; red2[tid] = vmin;
  __syncthreads();
  for (int s = 128; s > 0; s >>= 1) {
    if (tid < s) {
      red[tid] = fmaxf(red[tid], red[tid + s]);
      red2[tid] = fminf(red2[tid], red2[tid + s]);
    }
    __syncthreads();
  }
  const float rmax = red[0], rmin = red2[0];
  __syncthreads();

  float e[8];
  float lsum = 0.f;
#pragma unroll
  for (int k = 0; k < 8; ++k) {
    e[k] = expf(vals[k] - rmax);
    lsum += e[k];
  }
  red[tid] = lsum;
  __syncthreads();
  for (int s = 128; s > 0; s >>= 1) {
    if (tid < s) red[tid] += red[tid + s];
    __syncthreads();
  }
  const float rsum = red[0];
#pragma unroll
  for (int k = 0; k < 8; ++k) zrow[tid + (k << 8)] = e[k] / rsum;
  if (tid == 0) rowDelta[b] = (1.0f - expf(rmin - rmax)) / rsum;  // z_max - z_min
}

// ---------------- Transpose W [512,2048] -> Wt [2048,512] ----------------
__global__ __launch_bounds__(256) void transpose_kernel(const float* __restrict__ W,
                                                        float* __restrict__ Wt) {
  __shared__ float tile[32][33];
  const int tx = threadIdx.x & 31, ty = threadIdx.x >> 5;  // 32x8
  const int bx = blockIdx.x;  // along H (2048/32=64)
  const int by = blockIdx.y;  // along D (512/32=16)
#pragma unroll
  for (int i = 0; i < 32; i += 8)
    tile[ty + i][tx] = W[(size_t)(by * 32 + ty + i) * HDIM + bx * 32 + tx];
  __syncthreads();
#pragma unroll
  for (int i = 0; i < 32; i += 8)
    Wt[(size_t)(bx * 32 + ty + i) * DDIM + by * 32 + tx] = tile[tx][ty + i];
}

// ---------------- Threefry-2x32, key = (0, 42) ----------------
__device__ __forceinline__ void threefry_0_42(uint32_t x0, uint32_t x1,
                                              uint32_t& o0, uint32_t& o1) {
  const uint32_t ks0 = 0u, ks1 = 42u, ks2 = 0x1BD11BDAu ^ 0u ^ 42u;
  x0 += ks0; x1 += ks1;
#define TF_R(r) { x0 += x1; x1 = (x1 << (r)) | (x1 >> (32 - (r))); x1 ^= x0; }
  TF_R(13) TF_R(15) TF_R(26) TF_R(6)   x0 += ks1; x1 += ks2 + 1u;
  TF_R(17) TF_R(29) TF_R(16) TF_R(24)  x0 += ks2; x1 += ks0 + 2u;
  TF_R(13) TF_R(15) TF_R(26) TF_R(6)   x0 += ks0; x1 += ks1 + 3u;
  TF_R(17) TF_R(29) TF_R(16) TF_R(24)  x0 += ks1; x1 += ks2 + 4u;
  TF_R(13) TF_R(15) TF_R(26) TF_R(6)   x0 += ks2; x1 += ks0 + 5u;
#undef TF_R
  o0 = x0; o1 = x1;
}

// JAX uniform(tiny,1): u = ((bits>>9)|0x3f800000) as float - 1; 0 -> tiny
__device__ __forceinline__ float bits_to_u(uint32_t bits) {
  float f = __uint_as_float((bits >> 9) | 0x3f800000u) - 1.0f;
  return (f == 0.0f) ? 1.1754943508222875e-38f : f;
}

// ---------------- Sampler: argmax_h( gumbel + z ), partitionable threefry ----
// bits32[i] = o0 ^ o1, (o0,o1) = threefry2x32((0,42), (0, i)), i = r*2048 + h.
// u[8] stays in registers; reductions are wave-shuffle (wave=64) + 4-entry LDS
// cross-wave merge -> exactly 2 barriers per block (was ~24 + 12KB LDS).
__global__ __launch_bounds__(256) void sample_kernel(const float* __restrict__ z,
                                                     const float* __restrict__ rowDelta,
                                                     int* __restrict__ samp) {
  const int r = blockIdx.x;         // 0..65535 (flat row n*2048+b)
  const int b = r & (BDIM - 1);
  const int tid = threadIdx.x;
  const int lane = tid & 63;
  const int wav = tid >> 6;
  const float* zrow = z + (size_t)b * HDIM;

  __shared__ float wmax[4];
  __shared__ double wbest[4];
  __shared__ int wbh[4];

  const uint32_t base = (uint32_t)r << 11;
  float u[8];
  float m = 0.f;
#pragma unroll
  for (int k = 0; k < 8; ++k) {
    uint32_t o0, o1;
    threefry_0_42(0u, base + (uint32_t)(tid + (k << 8)), o0, o1);
    u[k] = bits_to_u(o0 ^ o1);
    m = fmaxf(m, u[k]);
  }
  // wave-level max, then cross-wave via 4-entry LDS
#pragma unroll
  for (int off = 32; off > 0; off >>= 1) m = fmaxf(m, __shfl_xor(m, off, 64));
  if (lane == 0) wmax[wav] = m;
  __syncthreads();
  const float umax = fmaxf(fmaxf(wmax[0], wmax[1]), fmaxf(wmax[2], wmax[3]));

  // conservative u-threshold: winner must have g(u) >= g(umax) - (zmax-zmin) - pad.
  // pad 3e-4 in g-space, minus 4 ulps in u-space for libm slop; `u == umax`
  // guard keeps the row-max unconditionally a candidate.
  const float dpad = rowDelta[b] + 3e-4f;
  float uthr = expf(-expf(-(-logf(-logf(umax)) - dpad)));
  uthr = __uint_as_float(__float_as_uint(uthr) - 4u);

  double best = -1e300; int bh = 0x7fffffff;
#pragma unroll
  for (int k = 0; k < 8; ++k) {
    const float uk = u[k];
    if (uk >= uthr || uk == umax) {
      const int hh = tid + (k << 8);
      double s = -log(-log((double)uk)) + (double)zrow[hh];
      if (s > best || (s == best && hh < bh)) { best = s; bh = hh; }
    }
  }
  // wave-level argmax reduce (first-index tie-break), then cross-wave
#pragma unroll
  for (int off = 32; off > 0; off >>= 1) {
    double so = __shfl_down(best, off, 64);
    int ho = __shfl_down(bh, off, 64);
    if (so > best || (so == best && ho < bh)) { best = so; bh = ho; }
  }
  if (lane == 0) { wbest[wav] = best; wbh[wav] = bh; }
  __syncthreads();
  if (tid == 0) {
#pragma unroll
    for (int w2 = 1; w2 < 4; ++w2) {
      if (wbest[w2] > best || (wbest[w2] == best && wbh[w2] < bh)) {
        best = wbest[w2]; bh = wbh[w2];
      }
    }
    samp[r] = bh;
  }
}

// faithful .T.reshape scramble: output row j uses samp_raw[j%32][j/32]
__device__ __forceinline__ int scrambled_samp(const int* samp, int j) {
  return samp[((j & 31) << 11) | (j >> 5)];
}

// ---------------- onehot: fused zero-fill + scatter (float4 streaming) --------
__global__ __launch_bounds__(256) void onehot_kernel(const int* __restrict__ samp,
                                                     float* __restrict__ oh) {
  const size_t idx4 = (size_t)blockIdx.x * 256 + threadIdx.x;  // 33554432 total
  const size_t el = idx4 << 2;
  const int j = (int)(el >> 11);        // 0..65535
  const int h0 = (int)(el & 2047);
  const int s = scrambled_samp(samp, j);
  const unsigned d = (unsigned)(s - h0);
  float4 v;
  v.x = (d == 0u) ? 1.f : 0.f;
  v.y = (d == 1u) ? 1.f : 0.f;
  v.z = (d == 2u) ? 1.f : 0.f;
  v.w = (d == 3u) ? 1.f : 0.f;
  ((float4*)oh)[idx4] = v;
}

// ---------------- x_decoded = Wt[s] (coalesced) + temp = coeff*exp(-0.5*ssq) --
__global__ __launch_bounds__(256) void xdec_kernel(const float* __restrict__ x,
                                                   const float* __restrict__ Wt,
                                                   const int* __restrict__ samp,
                                                   float* __restrict__ xd,
                                                   float* __restrict__ temp) {
  const int j = blockIdx.x * 2 + (threadIdx.x >> 7);  // 2 rows / block
  const int t = threadIdx.x & 127;                    // 128 float4 per row
  const int s = scrambled_samp(samp, j);
  const int c = j & (BDIM - 1);                       // x row index

  const float4 wv = ((const float4*)(Wt + (size_t)s * DDIM))[t];
  const float4 xv = ((const float4*)(x + (size_t)c * DDIM))[t];
  ((float4*)(xd + (size_t)j * DDIM))[t] = wv;

  const float dx = xv.x - wv.x, dy = xv.y - wv.y, dz = xv.z - wv.z, dw = xv.w - wv.w;
  float ss = dx * dx + dy * dy + dz * dz + dw * dw;

  __shared__ float sred[256];
  sred[threadIdx.x] = ss;
  __syncthreads();
  for (int st = 64; st > 0; st >>= 1) {
    if (t < st) sred[threadIdx.x] += sred[threadIdx.x + st];
    __syncthreads();
  }
  if (t == 0) temp[j] = 0.3989422804014327f * expf(-0.5f * sred[threadIdx.x]);
}

// ---------------- weight = temp / mean_n(temp) ----------------
__global__ __launch_bounds__(256) void weight_kernel(const float* __restrict__ temp,
                                                     float* __restrict__ wout) {
  const int c = blockIdx.x * 256 + threadIdx.x;  // 0..2047
  if (c >= BDIM) return;
  float sum = 0.f;
#pragma unroll
  for (int a = 0; a < NSAMP; ++a) sum += temp[a * BDIM + c];
  const float mean = sum / 32.0f;
#pragma unroll
  for (int a = 0; a < NSAMP; ++a) wout[a * BDIM + c] = temp[a * BDIM + c] / mean;
}

extern "C" void kernel_launch(void* const* d_in, const int* in_sizes, int n_in,
                              void* d_out, int out_size, void* d_ws, size_t ws_size,
                              hipStream_t stream) {
  (void)in_sizes; (void)n_in; (void)out_size; (void)ws_size;
  const float* x = (const float*)d_in[0];  // [2048,512]
  const float* W = (const float*)d_in[1];  // [512,2048]
  float* out = (float*)d_out;

  float* h  = out + OFF_H;
  float* z  = out + OFF_Z;
  float* oh = out + OFF_OH;
  float* xd = out + OFF_XD;
  float* wo = out + OFF_W;

  float* ws = (float*)d_ws;
  float* Wt = ws + WS_WT;
  int* samp = (int*)(ws + WS_SAMP);
  float* temp = ws + WS_TEMP;
  float* rowDelta = ws + WS_DELTA;

  gemm_kernel<<<dim3(32, 32), 256, 0, stream>>>(x, W, h);
  softmax_kernel<<<2048, 256, 0, stream>>>(h, z, rowDelta);
  transpose_kernel<<<dim3(64, 16), 256, 0, stream>>>(W, Wt);
  sample_kernel<<<65536, 256, 0, stream>>>(z, rowDelta, samp);
  onehot_kernel<<<131072, 256, 0, stream>>>(samp, oh);
  xdec_kernel<<<32768, 256, 0, stream>>>(x, Wt, samp, xd, temp);
  weight_kernel<<<8, 256, 0, stream>>>(temp, wo);
}

// Round 5
// 1019.652 us; speedup vs baseline: 1.0367x; 1.0367x over previous
//
#include <hip/hip_runtime.h>
#include <stdint.h>
#include <math.h>

// Problem dims
static constexpr int BDIM = 2048;   // batch B
static constexpr int HDIM = 2048;   // hidden H
static constexpr int DDIM = 512;    // input dim D
static constexpr int NSAMP = 32;    // N_SAMPLE

// d_out layout (float elements, concatenated in return order)
static constexpr size_t OFF_H  = 0;
static constexpr size_t OFF_Z  = (size_t)BDIM * HDIM;                  // 4194304
static constexpr size_t OFF_OH = OFF_Z + (size_t)BDIM * HDIM;          // 8388608
static constexpr size_t OFF_XD = OFF_OH + (size_t)NSAMP * BDIM * HDIM; // 142606336
static constexpr size_t OFF_W  = OFF_XD + (size_t)NSAMP * BDIM * DDIM; // 176160768

// d_ws layout (float offsets): Wt fp32 [2048*512], xb bf16 [2048*512],
// Wtb bf16 [2048*512] (n-major), samp int[65536], temp [65536], rowDelta [2048]
static constexpr size_t WS_WT    = 0;                          // 1048576 floats
static constexpr size_t WS_XB    = 1048576;                    // 524288 floats (1M ushort)
static constexpr size_t WS_WTB   = WS_XB + 524288;             // 524288 floats
static constexpr size_t WS_SAMP  = WS_WTB + 524288;
static constexpr size_t WS_TEMP  = WS_SAMP + 65536;
static constexpr size_t WS_DELTA = WS_TEMP + 65536;

typedef __attribute__((ext_vector_type(8))) short short8;
typedef __attribute__((ext_vector_type(4))) float f32x4;

__device__ __forceinline__ ushort f2bf(float f) {
  uint32_t x = __float_as_uint(f);
  return (ushort)((x + 0x7FFFu + ((x >> 16) & 1u)) >> 16);  // RNE, no NaN here
}

// ---------------- cast x -> bf16 ----------------
__global__ __launch_bounds__(256) void cast_x_kernel(const float* __restrict__ x,
                                                     ushort* __restrict__ xb) {
  const int i = (blockIdx.x * 256 + threadIdx.x) * 4;  // 1048576 elems
  float4 v = *(const float4*)(x + i);
  ushort4 o = {f2bf(v.x), f2bf(v.y), f2bf(v.z), f2bf(v.w)};
  *(ushort4*)(xb + i) = o;
}

// ------------- Transpose W [512,2048] -> Wt fp32 + Wtb bf16 [2048,512] -------
__global__ __launch_bounds__(256) void transpose_kernel(const float* __restrict__ W,
                                                        float* __restrict__ Wt,
                                                        ushort* __restrict__ Wtb) {
  __shared__ float tile[32][33];
  const int tx = threadIdx.x & 31, ty = threadIdx.x >> 5;  // 32x8
  const int bx = blockIdx.x;  // along H (2048/32=64)
  const int by = blockIdx.y;  // along D (512/32=16)
#pragma unroll
  for (int i = 0; i < 32; i += 8)
    tile[ty + i][tx] = W[(size_t)(by * 32 + ty + i) * HDIM + bx * 32 + tx];
  __syncthreads();
#pragma unroll
  for (int i = 0; i < 32; i += 8) {
    float v = tile[tx][ty + i];
    const size_t o = (size_t)(bx * 32 + ty + i) * DDIM + by * 32 + tx;
    Wt[o] = v;
    Wtb[o] = f2bf(v);
  }
}

// ---------------- GEMM: h = x @ W via bf16 MFMA (M=N=2048, K=512) -------------
// xb [M][K] bf16, wtb [N][K] bf16 (i.e. W^T) -> both A and B frags are
// k-contiguous short8 reads (m92-verified layout: A[m=lane&15][k=(lane>>4)*8+j],
// C/D: col=lane&15, row=(lane>>4)*4+reg).
__global__ __launch_bounds__(256) void gemm_mfma_kernel(const ushort* __restrict__ xb,
                                                        const ushort* __restrict__ wtb,
                                                        float* __restrict__ h) {
  __shared__ short As[128][72];  // pad 8 shorts (16B) keeps b128 align, spreads banks
  __shared__ short Bs[128][72];
  const int tid = threadIdx.x;
  const int bm = blockIdx.y * 128, bn = blockIdx.x * 128;
  const int wave = tid >> 6, lane = tid & 63;
  const int wm = (wave >> 1) * 64, wn = (wave & 1) * 64;  // 2x2 waves of 64x64
  const int lrow = lane & 15, lk = (lane >> 4) * 8;

  f32x4 acc[4][4] = {};

  const int srow = tid >> 3;         // 0..31
  const int scol = (tid & 7) * 8;    // 0..56

  for (int k0 = 0; k0 < DDIM; k0 += 64) {
#pragma unroll
    for (int p = 0; p < 4; ++p) {
      const int r = srow + p * 32;
      short8 av = *(const short8*)(xb + (size_t)(bm + r) * DDIM + k0 + scol);
      short8 bv = *(const short8*)(wtb + (size_t)(bn + r) * DDIM + k0 + scol);
      *(short8*)&As[r][scol] = av;
      *(short8*)&Bs[r][scol] = bv;
    }
    __syncthreads();
#pragma unroll
    for (int kk = 0; kk < 64; kk += 32) {
      short8 af[4], bf[4];
#pragma unroll
      for (int i = 0; i < 4; ++i) {
        af[i] = *(const short8*)&As[wm + i * 16 + lrow][kk + lk];
        bf[i] = *(const short8*)&Bs[wn + i * 16 + lrow][kk + lk];
      }
#pragma unroll
      for (int i = 0; i < 4; ++i)
#pragma unroll
        for (int j = 0; j < 4; ++j)
          acc[i][j] = __builtin_amdgcn_mfma_f32_16x16x32_bf16(af[i], bf[j], acc[i][j], 0, 0, 0);
    }
    __syncthreads();
  }
#pragma unroll
  for (int i = 0; i < 4; ++i)
#pragma unroll
    for (int j = 0; j < 4; ++j)
#pragma unroll
      for (int rg = 0; rg < 4; ++rg) {
        const int row = bm + wm + i * 16 + (lane >> 4) * 4 + rg;
        const int col = bn + wn + j * 16 + (lane & 15);
        h[(size_t)row * HDIM + col] = acc[i][j][rg];
      }
}

// ---------------- Softmax rows + per-row z-spread ----------------
__global__ __launch_bounds__(256) void softmax_kernel(const float* __restrict__ h,
                                                      float* __restrict__ z,
                                                      float* __restrict__ rowDelta) {
  const int b = blockIdx.x;
  const int tid = threadIdx.x;
  const float* row = h + (size_t)b * HDIM;
  float* zrow = z + (size_t)b * HDIM;
  __shared__ float red[256], red2[256];

  float vals[8];
  float vmax = -INFINITY, vmin = INFINITY;
#pragma unroll
  for (int k = 0; k < 8; ++k) {
    float v = row[tid + (k << 8)];
    vals[k] = v;
    vmax = fmaxf(vmax, v);
    vmin = fminf(vmin, v);
  }
  red[tid] = vmax; red2[tid] = vmin;
  __syncthreads();
  for (int s = 128; s > 0; s >>= 1) {
    if (tid < s) {
      red[tid] = fmaxf(red[tid], red[tid + s]);
      red2[tid] = fminf(red2[tid], red2[tid + s]);
    }
    __syncthreads();
  }
  const float rmax = red[0], rmin = red2[0];
  __syncthreads();

  float e[8];
  float lsum = 0.f;
#pragma unroll
  for (int k = 0; k < 8; ++k) {
    e[k] = expf(vals[k] - rmax);
    lsum += e[k];
  }
  red[tid] = lsum;
  __syncthreads();
  for (int s = 128; s > 0; s >>= 1) {
    if (tid < s) red[tid] += red[tid + s];
    __syncthreads();
  }
  const float rsum = red[0];
#pragma unroll
  for (int k = 0; k < 8; ++k) zrow[tid + (k << 8)] = e[k] / rsum;
  if (tid == 0) rowDelta[b] = (1.0f - expf(rmin - rmax)) / rsum;  // z_max - z_min
}

// ---------------- Threefry-2x32, key = (0, 42) ----------------
__device__ __forceinline__ void threefry_0_42(uint32_t x0, uint32_t x1,
                                              uint32_t& o0, uint32_t& o1) {
  const uint32_t ks0 = 0u, ks1 = 42u, ks2 = 0x1BD11BDAu ^ 0u ^ 42u;
  x0 += ks0; x1 += ks1;
#define TF_R(r) { x0 += x1; x1 = (x1 << (r)) | (x1 >> (32 - (r))); x1 ^= x0; }
  TF_R(13) TF_R(15) TF_R(26) TF_R(6)   x0 += ks1; x1 += ks2 + 1u;
  TF_R(17) TF_R(29) TF_R(16) TF_R(24)  x0 += ks2; x1 += ks0 + 2u;
  TF_R(13) TF_R(15) TF_R(26) TF_R(6)   x0 += ks0; x1 += ks1 + 3u;
  TF_R(17) TF_R(29) TF_R(16) TF_R(24)  x0 += ks1; x1 += ks2 + 4u;
  TF_R(13) TF_R(15) TF_R(26) TF_R(6)   x0 += ks2; x1 += ks0 + 5u;
#undef TF_R
  o0 = x0; o1 = x1;
}

// JAX uniform(tiny,1): u = ((bits>>9)|0x3f800000) as float - 1; 0 -> tiny
__device__ __forceinline__ float bits_to_u(uint32_t bits) {
  float f = __uint_as_float((bits >> 9) | 0x3f800000u) - 1.0f;
  return (f == 0.0f) ? 1.1754943508222875e-38f : f;
}

// ---------------- Sampler: argmax_h( gumbel + z ), partitionable threefry ----
// bits32[i] = o0 ^ o1, (o0,o1) = threefry2x32((0,42), (0, i)), i = r*2048 + h.
// Row-max & candidate screen in integer bit-space (u monotone in bits>>9);
// wave-shuffle reductions, 2 barriers/block.
__global__ __launch_bounds__(256) void sample_kernel(const float* __restrict__ z,
                                                     const float* __restrict__ rowDelta,
                                                     int* __restrict__ samp) {
  const int r = blockIdx.x;         // 0..65535 (flat row n*2048+b)
  const int b = r & (BDIM - 1);
  const int tid = threadIdx.x;
  const int lane = tid & 63;
  const int wav = tid >> 6;
  const float* zrow = z + (size_t)b * HDIM;

  __shared__ uint32_t wmax[4];
  __shared__ double wbest[4];
  __shared__ int wbh[4];

  const uint32_t base = (uint32_t)r << 11;
  uint32_t bb[8];
  uint32_t m23 = 0u;
#pragma unroll
  for (int k = 0; k < 8; ++k) {
    uint32_t o0, o1;
    threefry_0_42(0u, base + (uint32_t)(tid + (k << 8)), o0, o1);
    bb[k] = (o0 ^ o1) >> 9;
    m23 = max(m23, bb[k]);
  }
#pragma unroll
  for (int off = 32; off > 0; off >>= 1)
    m23 = max(m23, (uint32_t)__shfl_xor((int)m23, off, 64));
  if (lane == 0) wmax[wav] = m23;
  __syncthreads();
  m23 = max(max(wmax[0], wmax[1]), max(wmax[2], wmax[3]));
  const float umax = bits_to_u(m23 << 9);

  // conservative threshold: winner needs g(u) >= g(umax) - (zmax-zmin) - pad.
  // pad 3e-4 in g-space, -4 ulps u-space for libm slop, then to 23-bit space
  // (1+u has mantissa == bits>>9 exactly); m23-equality keeps row-max always in.
  const float dpad = rowDelta[b] + 3e-4f;
  float uthr = expf(-expf(-(-logf(-logf(umax)) - dpad)));
  uthr = __uint_as_float(__float_as_uint(uthr) - 4u);
  uint32_t thr23 = __float_as_uint(1.0f + uthr) & 0x7FFFFFu;
  if (thr23 > 0u) thr23 -= 1u;  // absorb 1+uthr rounding

  double best = -1e300; int bh = 0x7fffffff;
#pragma unroll
  for (int k = 0; k < 8; ++k) {
    if (bb[k] >= thr23 || bb[k] == m23) {
      const int hh = tid + (k << 8);
      const float uk = bits_to_u(bb[k] << 9);
      double s = -log(-log((double)uk)) + (double)zrow[hh];
      if (s > best || (s == best && hh < bh)) { best = s; bh = hh; }
    }
  }
#pragma unroll
  for (int off = 32; off > 0; off >>= 1) {
    double so = __shfl_down(best, off, 64);
    int ho = __shfl_down(bh, off, 64);
    if (so > best || (so == best && ho < bh)) { best = so; bh = ho; }
  }
  if (lane == 0) { wbest[wav] = best; wbh[wav] = bh; }
  __syncthreads();
  if (tid == 0) {
#pragma unroll
    for (int w2 = 1; w2 < 4; ++w2) {
      if (wbest[w2] > best || (wbest[w2] == best && wbh[w2] < bh)) {
        best = wbest[w2]; bh = wbh[w2];
      }
    }
    samp[r] = bh;
  }
}

// faithful .T.reshape scramble: output row j uses samp_raw[j%32][j/32]
__device__ __forceinline__ int scrambled_samp(const int* samp, int j) {
  return samp[((j & 31) << 11) | (j >> 5)];
}

// ---------------- onehot: fused zero-fill + scatter (float4 streaming) --------
__global__ __launch_bounds__(256) void onehot_kernel(const int* __restrict__ samp,
                                                     float* __restrict__ oh) {
  const size_t idx4 = (size_t)blockIdx.x * 256 + threadIdx.x;  // 33554432 total
  const size_t el = idx4 << 2;
  const int j = (int)(el >> 11);        // 0..65535
  const int h0 = (int)(el & 2047);
  const int s = scrambled_samp(samp, j);
  const unsigned d = (unsigned)(s - h0);
  float4 v;
  v.x = (d == 0u) ? 1.f : 0.f;
  v.y = (d == 1u) ? 1.f : 0.f;
  v.z = (d == 2u) ? 1.f : 0.f;
  v.w = (d == 3u) ? 1.f : 0.f;
  ((float4*)oh)[idx4] = v;
}

// ---------------- x_decoded = Wt[s] (coalesced) + temp = coeff*exp(-0.5*ssq) --
__global__ __launch_bounds__(256) void xdec_kernel(const float* __restrict__ x,
                                                   const float* __restrict__ Wt,
                                                   const int* __restrict__ samp,
                                                   float* __restrict__ xd,
                                                   float* __restrict__ temp) {
  const int j = blockIdx.x * 2 + (threadIdx.x >> 7);  // 2 rows / block
  const int t = threadIdx.x & 127;                    // 128 float4 per row
  const int s = scrambled_samp(samp, j);
  const int c = j & (BDIM - 1);                       // x row index

  const float4 wv = ((const float4*)(Wt + (size_t)s * DDIM))[t];
  const float4 xv = ((const float4*)(x + (size_t)c * DDIM))[t];
  ((float4*)(xd + (size_t)j * DDIM))[t] = wv;

  const float dx = xv.x - wv.x, dy = xv.y - wv.y, dz = xv.z - wv.z, dw = xv.w - wv.w;
  float ss = dx * dx + dy * dy + dz * dz + dw * dw;

  __shared__ float sred[256];
  sred[threadIdx.x] = ss;
  __syncthreads();
  for (int st = 64; st > 0; st >>= 1) {
    if (t < st) sred[threadIdx.x] += sred[threadIdx.x + st];
    __syncthreads();
  }
  if (t == 0) temp[j] = 0.3989422804014327f * expf(-0.5f * sred[threadIdx.x]);
}

// ---------------- weight = temp / mean_n(temp) ----------------
__global__ __launch_bounds__(256) void weight_kernel(const float* __restrict__ temp,
                                                     float* __restrict__ wout) {
  const int c = blockIdx.x * 256 + threadIdx.x;  // 0..2047
  if (c >= BDIM) return;
  float sum = 0.f;
#pragma unroll
  for (int a = 0; a < NSAMP; ++a) sum += temp[a * BDIM + c];
  const float mean = sum / 32.0f;
#pragma unroll
  for (int a = 0; a < NSAMP; ++a) wout[a * BDIM + c] = temp[a * BDIM + c] / mean;
}

extern "C" void kernel_launch(void* const* d_in, const int* in_sizes, int n_in,
                              void* d_out, int out_size, void* d_ws, size_t ws_size,
                              hipStream_t stream) {
  (void)in_sizes; (void)n_in; (void)out_size; (void)ws_size;
  const float* x = (const float*)d_in[0];  // [2048,512]
  const float* W = (const float*)d_in[1];  // [512,2048]
  float* out = (float*)d_out;

  float* h  = out + OFF_H;
  float* z  = out + OFF_Z;
  float* oh = out + OFF_OH;
  float* xd = out + OFF_XD;
  float* wo = out + OFF_W;

  float* ws = (float*)d_ws;
  float* Wt = ws + WS_WT;
  ushort* xb = (ushort*)(ws + WS_XB);
  ushort* Wtb = (ushort*)(ws + WS_WTB);
  int* samp = (int*)(ws + WS_SAMP);
  float* temp = ws + WS_TEMP;
  float* rowDelta = ws + WS_DELTA;

  cast_x_kernel<<<1024, 256, 0, stream>>>(x, xb);
  transpose_kernel<<<dim3(64, 16), 256, 0, stream>>>(W, Wt, Wtb);
  gemm_mfma_kernel<<<dim3(16, 16), 256, 0, stream>>>(xb, Wtb, h);
  softmax_kernel<<<2048, 256, 0, stream>>>(h, z, rowDelta);
  sample_kernel<<<65536, 256, 0, stream>>>(z, rowDelta, samp);
  onehot_kernel<<<131072, 256, 0, stream>>>(samp, oh);
  xdec_kernel<<<32768, 256, 0, stream>>>(x, Wt, samp, xd, temp);
  weight_kernel<<<8, 256, 0, stream>>>(temp, wo);
}